// Round 1
// 1687.388 us; speedup vs baseline: 1.0361x; 1.0361x over previous
//
#include <hip/hip_runtime.h>
#include <stdint.h>

#define BB 2
#define CC 256
#define HH 200
#define WW 336
#define NROI 512
#define NCLS 81

typedef __attribute__((ext_vector_type(8))) short bf16x8;
typedef __attribute__((ext_vector_type(4))) float f32x4;

__device__ inline unsigned short f2bf(float f) {
  unsigned int u = __builtin_bit_cast(unsigned int, f);
  u += 0x7fffu + ((u >> 16) & 1u);
  return (unsigned short)(u >> 16);
}
__device__ inline float bf2f(unsigned short h) {
  unsigned int u = ((unsigned int)h) << 16;
  return __builtin_bit_cast(float, u);
}

// async global->LDS, 16 B per lane; LDS dest = uniform base + lane*16
__device__ inline void gl_lds(const void* gp, void* lp) {
  __builtin_amdgcn_global_load_lds(
      (const __attribute__((address_space(1))) unsigned int*)gp,
      (__attribute__((address_space(3))) unsigned int*)lp, 16, 0, 0);
}

// ---------------------------------------------------------------------------
// feat NCHW fp32 -> NHWC bf16, tiled transpose. grid (2100, 8, 2), block 256
// ---------------------------------------------------------------------------
__global__ void k_nchw2nhwc(const float* __restrict__ src, unsigned short* __restrict__ dst) {
  __shared__ float t[32][33];
  int b = blockIdx.z;
  int p0 = blockIdx.x * 32;
  int c0 = blockIdx.y * 32;
  int tx = threadIdx.x & 31, ty = threadIdx.x >> 5;
  const float* s = src + (size_t)b * CC * HH * WW;
  unsigned short* d = dst + (size_t)b * CC * HH * WW;
#pragma unroll
  for (int q = 0; q < 4; ++q)
    t[ty + q * 8][tx] = s[(size_t)(c0 + ty + q * 8) * (HH * WW) + p0 + tx];
  __syncthreads();
#pragma unroll
  for (int q = 0; q < 4; ++q)
    d[(size_t)(p0 + ty + q * 8) * CC + c0 + tx] = f2bf(t[tx][ty + q * 8]);
}

// ---------------------------------------------------------------------------
// Weight repacks (fp32 -> bf16, Bt layout [out][in] so GEMM reads k-contig)
// ---------------------------------------------------------------------------
// 4 conv weights OIHW [256,256,3,3] -> wTb[conv][t][o][c]; grid (2304, 4)
__global__ void k_repack_convw4(const float* __restrict__ w0, const float* __restrict__ w1,
                                const float* __restrict__ w2, const float* __restrict__ w3,
                                unsigned short* __restrict__ wT) {
  int d = blockIdx.x * 256 + threadIdx.x;  // 9*256*256
  if (d >= 589824) return;
  int which = blockIdx.y;
  const float* w = (which == 0) ? w0 : (which == 1) ? w1 : (which == 2) ? w2 : w3;
  int c = d & 255, o = (d >> 8) & 255, t = d >> 16;
  wT[(size_t)which * 589824 + d] = f2bf(w[o * 2304 + c * 9 + t]);
}

// deconv IOHW [256,256,2,2] -> wdb[tap][o][c], spatially flipped:
// out[2i+r,2j+s,o] += x[i,j,c]*mdc[c,o,1-r,1-s]
__global__ void k_repack_deconv(const float* __restrict__ mdc, unsigned short* __restrict__ wd) {
  int d = blockIdx.x * 256 + threadIdx.x;  // 4*256*256
  if (d >= 262144) return;
  int c = d & 255, o = (d >> 8) & 255, tap = d >> 16;
  int r = tap >> 1, s = tap & 1;
  wd[d] = f2bf(mdc[c * 1024 + o * 4 + (1 - r) * 2 + (1 - s)]);
}

// mpr [81,256] -> mprTb[o][c], o padded to 128 with zeros
__global__ void k_repack_mpr(const float* __restrict__ mpr, unsigned short* __restrict__ mT) {
  int d = blockIdx.x * 256 + threadIdx.x;  // 128*256
  if (d >= 32768) return;
  int c = d & 255, o = d >> 8;
  mT[d] = (o < 81) ? f2bf(mpr[o * 256 + c]) : (unsigned short)0;
}

// w1 [12544][1024] -> dst[n][k'] with k' = s*256 + c  (orig k = c*49+s)
// grid (49, 8, 32), block 256
__global__ void k_repack_w1(const float* __restrict__ src, unsigned short* __restrict__ dst) {
  __shared__ float t[32][33];
  int s = blockIdx.x;
  int c0 = blockIdx.y * 32;
  int n0 = blockIdx.z * 32;
  int tx = threadIdx.x & 31, ty = threadIdx.x >> 5;
#pragma unroll
  for (int q = 0; q < 4; ++q)
    t[ty + q * 8][tx] = src[(size_t)((c0 + ty + q * 8) * 49 + s) * 1024 + n0 + tx];
  __syncthreads();
#pragma unroll
  for (int q = 0; q < 4; ++q)
    dst[(size_t)(n0 + ty + q * 8) * 12544 + s * 256 + c0 + tx] = f2bf(t[tx][ty + q * 8]);
}

// generic: src [K][Nreal] f32 -> dst [Nphys][K] bf16 (rows >= Nreal zero)
__global__ void k_transpose_w(const float* __restrict__ src, unsigned short* __restrict__ dst,
                              int K, int Nreal, int Nphys) {
  __shared__ float t[32][33];
  int k0 = blockIdx.x * 32;
  int n0 = blockIdx.y * 32;
  int tx = threadIdx.x & 31, ty = threadIdx.x >> 5;
#pragma unroll
  for (int q = 0; q < 4; ++q) {
    int n = n0 + tx;
    t[ty + q * 8][tx] = (n < Nreal) ? src[(size_t)(k0 + ty + q * 8) * Nreal + n] : 0.f;
  }
  __syncthreads();
#pragma unroll
  for (int q = 0; q < 4; ++q) {
    int n = n0 + ty + q * 8;
    if (n < Nphys) dst[(size_t)n * K + k0 + tx] = f2bf(t[tx][ty + q * 8]);
  }
}

// ---------------------------------------------------------------------------
// zero the 60 border slots (16x16 pad minus 14x14 interior) of the 3 padded
// NHWC conv buffers. grid (480, 3), block 256; each block = 64 rows of 512 B.
// ---------------------------------------------------------------------------
__global__ void k_zero_border(unsigned short* __restrict__ r14p,
                              unsigned short* __restrict__ cbufA,
                              unsigned short* __restrict__ cbufB) {
  unsigned short* base = (blockIdx.y == 0) ? r14p : (blockIdx.y == 1) ? cbufA : cbufB;
  uint4 z = {0u, 0u, 0u, 0u};
#pragma unroll
  for (int q = 0; q < 8; ++q) {
    int lin = blockIdx.x * 2048 + q * 256 + threadIdx.x;
    int row = lin >> 5, u4 = lin & 31;
    int img = row / 60, b = row - img * 60;
    int y, x;
    if (b < 16) { y = 0; x = b; }
    else if (b < 32) { y = 15; x = b - 16; }
    else { int rem = b - 32; y = 1 + (rem >> 1); x = (rem & 1) * 15; }
    int slot = img * 256 + y * 16 + x;
    ((uint4*)base)[(size_t)slot * 32 + u4] = z;
  }
}

// ---------------------------------------------------------------------------
// RoIAlign from bf16 NHWC feat, bf16 out. Block per (n, s), 256 thr = channels.
// OS=7 : out r7b[n*12544 + s*256 + c]           (FC-head A, k' = s*256+c)
// OS=14: out r14p[(n*256 + (y+1)*16 + (x+1))*256 + c]  (padded conv input)
// ---------------------------------------------------------------------------
template <int OS>
__global__ void k_roialign(const unsigned short* __restrict__ featN, const float* __restrict__ boxes,
                           const int* __restrict__ bidx, unsigned short* __restrict__ out) {
  const int S = OS * OS;
  int blk = blockIdx.x;
  int n = blk / S;
  int s = blk - n * S;
  int oy = s / OS, ox = s - oy * OS;
  int c = threadIdx.x;
  float x1 = boxes[n * 4 + 0], y1 = boxes[n * 4 + 1];
  float x2 = boxes[n * 4 + 2], y2 = boxes[n * 4 + 3];
  const unsigned short* fb = featN + (size_t)bidx[n] * HH * WW * CC;
  const float P = (float)(OS * 2);
  float acc = 0.f;
#pragma unroll
  for (int sy = 0; sy < 2; ++sy)
#pragma unroll
    for (int sx = 0; sx < 2; ++sx) {
      float xs = x1 + ((float)(ox * 2 + sx) + 0.5f) / P * (x2 - x1);
      float ys = y1 + ((float)(oy * 2 + sy) + 0.5f) / P * (y2 - y1);
      xs = fminf(fmaxf(xs, 0.f), (float)(WW - 1));
      ys = fminf(fmaxf(ys, 0.f), (float)(HH - 1));
      int x0 = (int)floorf(xs);
      int y0 = (int)floorf(ys);
      int x1i = min(x0 + 1, WW - 1);
      int y1i = min(y0 + 1, HH - 1);
      float lx = xs - (float)x0, ly = ys - (float)y0;
      float f00 = bf2f(fb[((y0 * WW + x0) << 8) + c]);
      float f01 = bf2f(fb[((y0 * WW + x1i) << 8) + c]);
      float f10 = bf2f(fb[((y1i * WW + x0) << 8) + c]);
      float f11 = bf2f(fb[((y1i * WW + x1i) << 8) + c]);
      acc += f00 * (1.f - ly) * (1.f - lx) + f01 * (1.f - ly) * lx +
             f10 * ly * (1.f - lx) + f11 * ly * lx;
    }
  acc *= 0.25f;
  if (OS == 7) {
    out[(size_t)n * 12544 + s * 256 + c] = f2bf(acc);
  } else {
    int slot = n * 256 + (oy + 1) * 16 + (ox + 1);
    out[((size_t)slot << 8) + c] = f2bf(acc);
  }
}

// ---------------------------------------------------------------------------
// bf16 MFMA GEMM, m97 structure: 128x128 tile, BK=32, 4 waves 2x2,
// global_load_lds width 16, A [M][K] bf16, Bt [Nphys][K] bf16.
// mode 0: bf16 out [gm*ldO+gn] (opt relu)
// mode 1: fp32 out [gm*ldO+gn], guarded gn < Nreal
// mode 2: fp32 mask-scatter, guarded gn < Nreal
// ---------------------------------------------------------------------------
#define TM 128
#define TN 128
#define TK 32

__global__ __launch_bounds__(256) void k_gemm_bf16(
    const unsigned short* __restrict__ A0, const unsigned short* __restrict__ Bt0, void* __restrict__ O0p,
    const unsigned short* __restrict__ A1, const unsigned short* __restrict__ Bt1, void* __restrict__ O1p,
    int K, int Nreal, int ldO, int mode, int relu, int ki, int kj) {
  const unsigned short* A = blockIdx.z ? A1 : A0;
  const unsigned short* Bt = blockIdx.z ? Bt1 : Bt0;
  void* Op = blockIdx.z ? O1p : O0p;

  __shared__ unsigned short As[TM * TK];
  __shared__ unsigned short Bs[TN * TK];

  int tid = threadIdx.x, lane = tid & 63, w = tid >> 6;
  int m0 = blockIdx.y * TM, n0 = blockIdx.x * TN;
  int lr = lane >> 2, lc = (lane & 3) * 8;

  const unsigned short* aP[2];
  const unsigned short* bP[2];
  unsigned short* asL[2];
  unsigned short* bsL[2];
#pragma unroll
  for (int s = 0; s < 2; ++s) {
    int seg = w * 2 + s;
    aP[s] = A + (size_t)(m0 + seg * 16 + lr) * K + lc;
    bP[s] = Bt + (size_t)(n0 + seg * 16 + lr) * K + lc;
    asL[s] = As + seg * 512;
    bsL[s] = Bs + seg * 512;
  }

  f32x4 acc[4][4] = {};
  int wm = (w & 1) * 64, wn = (w >> 1) * 64;
  int qa = (lane >> 4) * 8, rl = lane & 15;

  for (int k0 = 0; k0 < K; k0 += TK) {
    gl_lds(aP[0], asL[0]);
    gl_lds(aP[1], asL[1]);
    gl_lds(bP[0], bsL[0]);
    gl_lds(bP[1], bsL[1]);
    aP[0] += TK; aP[1] += TK; bP[0] += TK; bP[1] += TK;
    __syncthreads();
    bf16x8 af[4], bfr[4];
#pragma unroll
    for (int i = 0; i < 4; ++i)
      af[i] = *(const bf16x8*)&As[(wm + i * 16 + rl) * TK + qa];
#pragma unroll
    for (int j = 0; j < 4; ++j)
      bfr[j] = *(const bf16x8*)&Bs[(wn + j * 16 + rl) * TK + qa];
#pragma unroll
    for (int i = 0; i < 4; ++i)
#pragma unroll
      for (int j = 0; j < 4; ++j)
        acc[i][j] = __builtin_amdgcn_mfma_f32_16x16x32_bf16(af[i], bfr[j], acc[i][j], 0, 0, 0);
    __syncthreads();
  }

  int col = lane & 15, rquad = (lane >> 4) * 4;
#pragma unroll
  for (int i = 0; i < 4; ++i) {
#pragma unroll
    for (int j = 0; j < 4; ++j) {
      int gn = n0 + wn + j * 16 + col;
#pragma unroll
      for (int r = 0; r < 4; ++r) {
        int gm = m0 + wm + i * 16 + rquad + r;
        float v = acc[i][j][r];
        if (relu) v = fmaxf(v, 0.f);
        if (mode == 0) {
          ((unsigned short*)Op)[(size_t)gm * ldO + gn] = f2bf(v);
        } else if (mode == 1) {
          if (gn < Nreal) ((float*)Op)[(size_t)gm * ldO + gn] = v;
        } else {
          if (gn < Nreal) {
            int nimg = gm / 196;
            int s2 = gm - nimg * 196;
            int ii = s2 / 14, jj = s2 - ii * 14;
            size_t dst = (((size_t)nimg * 81 + gn) * 28 + (2 * ii + ki)) * 28 + (2 * jj + kj);
            ((float*)Op)[dst] = v;
          }
        }
      }
    }
  }
}

// ---------------------------------------------------------------------------
// FC1 split-K: M=512, N=1024, K=12544 split into 8 slices of 1568.
// grid (8, 4, 16): z -> head = z>>3 (0:box 1:cls), slice = z&7.
// fp32 partials Opart[(head*8+slice)*524288 + m*1024 + n].
// ---------------------------------------------------------------------------
__global__ __launch_bounds__(256) void k_fc1(
    const unsigned short* __restrict__ A, const unsigned short* __restrict__ Bb,
    const unsigned short* __restrict__ Bc, float* __restrict__ Opart) {
  int head = blockIdx.z >> 3, slice = blockIdx.z & 7;
  const unsigned short* Bt = head ? Bc : Bb;

  __shared__ unsigned short As[TM * TK];
  __shared__ unsigned short Bs[TN * TK];

  int tid = threadIdx.x, lane = tid & 63, w = tid >> 6;
  int m0 = blockIdx.y * TM, n0 = blockIdx.x * TN;
  int lr = lane >> 2, lc = (lane & 3) * 8;
  int kbase = slice * 1568;

  const unsigned short* aP[2];
  const unsigned short* bP[2];
  unsigned short* asL[2];
  unsigned short* bsL[2];
#pragma unroll
  for (int s = 0; s < 2; ++s) {
    int seg = w * 2 + s;
    aP[s] = A + (size_t)(m0 + seg * 16 + lr) * 12544 + kbase + lc;
    bP[s] = Bt + (size_t)(n0 + seg * 16 + lr) * 12544 + kbase + lc;
    asL[s] = As + seg * 512;
    bsL[s] = Bs + seg * 512;
  }

  f32x4 acc[4][4] = {};
  int wm = (w & 1) * 64, wn = (w >> 1) * 64;
  int qa = (lane >> 4) * 8, rl = lane & 15;

  for (int k0 = 0; k0 < 1568; k0 += TK) {
    gl_lds(aP[0], asL[0]);
    gl_lds(aP[1], asL[1]);
    gl_lds(bP[0], bsL[0]);
    gl_lds(bP[1], bsL[1]);
    aP[0] += TK; aP[1] += TK; bP[0] += TK; bP[1] += TK;
    __syncthreads();
    bf16x8 af[4], bfr[4];
#pragma unroll
    for (int i = 0; i < 4; ++i)
      af[i] = *(const bf16x8*)&As[(wm + i * 16 + rl) * TK + qa];
#pragma unroll
    for (int j = 0; j < 4; ++j)
      bfr[j] = *(const bf16x8*)&Bs[(wn + j * 16 + rl) * TK + qa];
#pragma unroll
    for (int i = 0; i < 4; ++i)
#pragma unroll
      for (int j = 0; j < 4; ++j)
        acc[i][j] = __builtin_amdgcn_mfma_f32_16x16x32_bf16(af[i], bfr[j], acc[i][j], 0, 0, 0);
    __syncthreads();
  }

  float* O = Opart + (size_t)(head * 8 + slice) * 524288;
  int col = lane & 15, rquad = (lane >> 4) * 4;
#pragma unroll
  for (int i = 0; i < 4; ++i)
#pragma unroll
    for (int j = 0; j < 4; ++j) {
      int gn = n0 + wn + j * 16 + col;
#pragma unroll
      for (int r = 0; r < 4; ++r) {
        int gm = m0 + wm + i * 16 + rquad + r;
        O[(size_t)gm * 1024 + gn] = acc[i][j][r];
      }
    }
}

// reduce 8 split-K partials, relu, -> bf16 h1. grid (2048, 2), block 256.
__global__ void k_fc1red(const float* __restrict__ part, unsigned short* __restrict__ h1b,
                         unsigned short* __restrict__ h1c) {
  int head = blockIdx.y;
  int i = blockIdx.x * 256 + threadIdx.x;  // < 524288
  const float* p = part + (size_t)head * 8 * 524288 + i;
  float s = 0.f;
#pragma unroll
  for (int q = 0; q < 8; ++q) s += p[(size_t)q * 524288];
  unsigned short* h = head ? h1c : h1b;
  h[i] = f2bf(fmaxf(s, 0.f));
}

// ---------------------------------------------------------------------------
// conv3x3 SAME + relu as implicit bf16 MFMA GEMM over padded NHWC input.
// act: [512*256 slots][256] bf16 (16x16 padded spatial); wt: [9][o][c] bf16.
// M = 100352 (grid.y=784), N = 256 (grid.x=2), K = 9*256.
// K-loop is CHANNELS-OUTER, TAPS-INNER: the 9 taps of one 32-ch slice touch
// ~10 KB of act per block (vs 82 KB per tap-pass in taps-outer order), so
// cross-tap reuse lands in L2 instead of thrashing it (FETCH was 13x unique).
// Block ids are XCD-chunk swizzled (1568 blocks % 8 == 0, bijective): each
// XCD gets 98 consecutive y-tiles x both x-blocks -> x-pairs that read
// identical A share one L2, halo rows shared between y-neighbors.
// PADOUT=1: write padded interior; PADOUT=0: flat [100352][256].
// ---------------------------------------------------------------------------
template <int PADOUT>
__global__ __launch_bounds__(256) void k_conv3m(const unsigned short* __restrict__ act,
                                                const unsigned short* __restrict__ wt,
                                                unsigned short* __restrict__ out) {
  __shared__ unsigned short As[TM * TK];
  __shared__ unsigned short Bs[TN * TK];

  int tid = threadIdx.x, lane = tid & 63, w = tid >> 6;
  // XCD-chunk swizzle of the (x,y) plane: 1568 blocks, 196 per XCD.
  int bid = blockIdx.y * 2 + blockIdx.x;
  int l = (bid & 7) * 196 + (bid >> 3);
  int bx = l & 1, by = l >> 1;
  int m0 = by * TM, n0 = bx * TN;
  int lr = lane >> 2, lc = (lane & 3) * 8;

  const unsigned short* aB[2];
  const unsigned short* bB[2];
  unsigned short* asL[2];
  unsigned short* bsL[2];
#pragma unroll
  for (int s = 0; s < 2; ++s) {
    int seg = w * 2 + s;
    int m = m0 + seg * 16 + lr;
    int n = m / 196;
    int rem = m - n * 196;
    int y = rem / 14, x = rem - y * 14;
    int slot = n * 256 + (y + 1) * 16 + (x + 1);
    aB[s] = act + ((size_t)slot << 8) + lc;
    bB[s] = wt + (size_t)(n0 + seg * 16 + lr) * 256 + lc;
    asL[s] = As + seg * 512;
    bsL[s] = Bs + seg * 512;
  }

  f32x4 acc[4][4] = {};
  int wm = (w & 1) * 64, wn = (w >> 1) * 64;
  int qa = (lane >> 4) * 8, rl = lane & 15;

  for (int c0 = 0; c0 < 256; c0 += TK) {
    for (int t = 0; t < 9; ++t) {
      int ky = t / 3, kx = t - ky * 3;  // 0..2 each
      int aoff = ((ky - 1) * 16 + (kx - 1)) * 256 + c0;
      int boff = t * 65536 + c0;
      gl_lds(aB[0] + aoff, asL[0]);
      gl_lds(aB[1] + aoff, asL[1]);
      gl_lds(bB[0] + boff, bsL[0]);
      gl_lds(bB[1] + boff, bsL[1]);
      __syncthreads();
      bf16x8 af[4], bfr[4];
#pragma unroll
      for (int i = 0; i < 4; ++i)
        af[i] = *(const bf16x8*)&As[(wm + i * 16 + rl) * TK + qa];
#pragma unroll
      for (int j = 0; j < 4; ++j)
        bfr[j] = *(const bf16x8*)&Bs[(wn + j * 16 + rl) * TK + qa];
#pragma unroll
      for (int i = 0; i < 4; ++i)
#pragma unroll
        for (int j = 0; j < 4; ++j)
          acc[i][j] = __builtin_amdgcn_mfma_f32_16x16x32_bf16(af[i], bfr[j], acc[i][j], 0, 0, 0);
      __syncthreads();
    }
  }

  int col = lane & 15, rquad = (lane >> 4) * 4;
#pragma unroll
  for (int i = 0; i < 4; ++i) {
#pragma unroll
    for (int r = 0; r < 4; ++r) {
      int gm = m0 + wm + i * 16 + rquad + r;
      size_t rowbase;
      if (PADOUT) {
        int n = gm / 196;
        int rem = gm - n * 196;
        int y = rem / 14, x = rem - y * 14;
        rowbase = ((size_t)(n * 256 + (y + 1) * 16 + (x + 1))) << 8;
      } else {
        rowbase = (size_t)gm << 8;
      }
#pragma unroll
      for (int j = 0; j < 4; ++j) {
        int gn = n0 + wn + j * 16 + col;
        out[rowbase + gn] = f2bf(fmaxf(acc[i][j][r], 0.f));
      }
    }
  }
}

// ---------------------------------------------------------------------------
// kernel_launch
// ---------------------------------------------------------------------------
extern "C" void kernel_launch(void* const* d_in, const int* in_sizes, int n_in,
                              void* d_out, int out_size, void* d_ws, size_t ws_size,
                              hipStream_t stream) {
  (void)in_sizes; (void)n_in; (void)out_size; (void)ws_size;
  const float* feat = (const float*)d_in[0];
  const float* boxes = (const float*)d_in[1];
  const float* bw1 = (const float*)d_in[2];
  const float* bw2 = (const float*)d_in[3];
  const float* bwo = (const float*)d_in[4];
  const float* cw1 = (const float*)d_in[5];
  const float* cw2 = (const float*)d_in[6];
  const float* cwo = (const float*)d_in[7];
  const float* m1 = (const float*)d_in[8];
  const float* m2 = (const float*)d_in[9];
  const float* m3 = (const float*)d_in[10];
  const float* m4 = (const float*)d_in[11];
  const float* mdc = (const float*)d_in[12];
  const float* mpr = (const float*)d_in[13];
  const int* bidx = (const int*)d_in[14];

  // ---- workspace layout (bytes; total 384,761,856 <= proven 386,465,792) ----
  char* p = (char*)d_ws;
  unsigned short* featN = (unsigned short*)p; p += 68812800;  // bf16 NHWC feat
  unsigned short* cbufA = featN;                              // alias (67,108,864 B)
  unsigned short* cbufB = (unsigned short*)p; p += 67108864;
  float* fc1part = (float*)cbufB;                             // alias (33,554,432 B)
  unsigned short* r14p = (unsigned short*)p;  p += 67108864;  // padded conv input
  unsigned short* dflat = (unsigned short*)p; p += 51380224;  // conv4 out, flat
  unsigned short* ddec = (unsigned short*)p;  p += 51380224;  // deconv tap out
  unsigned short* r7b = (unsigned short*)p;   p += 12845056;  // [512][12544]
  unsigned short* h1b = (unsigned short*)p;   p += 1048576;
  unsigned short* h1c = (unsigned short*)p;   p += 1048576;
  unsigned short* h2b = (unsigned short*)p;   p += 1048576;
  unsigned short* h2c = (unsigned short*)p;   p += 1048576;
  unsigned short* wTb = (unsigned short*)p;   p += 4718592;   // 4 convs [9][o][c]
  unsigned short* wdb = (unsigned short*)p;   p += 524288;    // [4][o][c]
  unsigned short* mprTb = (unsigned short*)p; p += 65536;     // [128][256]
  unsigned short* bw1b = (unsigned short*)p;  p += 25690112;  // [1024][12544]
  unsigned short* cw1b = (unsigned short*)p;  p += 25690112;
  unsigned short* bw2b = (unsigned short*)p;  p += 2097152;   // [1024][1024]
  unsigned short* cw2b = (unsigned short*)p;  p += 2097152;
  unsigned short* bwob = (unsigned short*)p;  p += 786432;    // [384][1024]
  unsigned short* cwob = (unsigned short*)p;  p += 262144;    // [128][1024]

  float* outBox = (float*)d_out;              // [512][324]
  float* outCls = outBox + 512 * 324;         // [512][81]
  float* outMask = outCls + 512 * 81;         // [512][81][28][28]

  // ---- stage 0: layout transforms ----
  k_nchw2nhwc<<<dim3(2100, 8, 2), 256, 0, stream>>>(feat, featN);
  k_repack_convw4<<<dim3(2304, 4), 256, 0, stream>>>(m1, m2, m3, m4, wTb);
  k_repack_deconv<<<dim3(1024), 256, 0, stream>>>(mdc, wdb);
  k_repack_mpr<<<dim3(128), 256, 0, stream>>>(mpr, mprTb);
  k_repack_w1<<<dim3(49, 8, 32), 256, 0, stream>>>(bw1, bw1b);
  k_repack_w1<<<dim3(49, 8, 32), 256, 0, stream>>>(cw1, cw1b);
  k_transpose_w<<<dim3(32, 32), 256, 0, stream>>>(bw2, bw2b, 1024, 1024, 1024);
  k_transpose_w<<<dim3(32, 32), 256, 0, stream>>>(cw2, cw2b, 1024, 1024, 1024);
  k_transpose_w<<<dim3(32, 12), 256, 0, stream>>>(bwo, bwob, 1024, 324, 384);
  k_transpose_w<<<dim3(32, 4), 256, 0, stream>>>(cwo, cwob, 1024, 81, 128);

  // ---- stage 1: RoIAlign (interiors; borders of r14p zeroed later) ----
  k_roialign<7><<<dim3(512 * 49), 256, 0, stream>>>(featN, boxes, bidx, r7b);
  k_roialign<14><<<dim3(512 * 196), 256, 0, stream>>>(featN, boxes, bidx, r14p);

  // ---- stage 2: FC heads. FC1 split-K=8 over both heads (partials alias cbufB) ----
  k_fc1<<<dim3(8, 4, 16), 256, 0, stream>>>(r7b, bw1b, cw1b, fc1part);
  k_fc1red<<<dim3(2048, 2), 256, 0, stream>>>(fc1part, h1b, h1c);
  k_gemm_bf16<<<dim3(8, 4, 2), 256, 0, stream>>>(h1b, bw2b, h2b, h1c, cw2b, h2c,
                                                 1024, 1024, 1024, 0, 1, 0, 0);
  k_gemm_bf16<<<dim3(3, 4, 1), 256, 0, stream>>>(h2b, bwob, outBox, h2b, bwob, outBox,
                                                 1024, 324, 324, 1, 0, 0, 0);
  k_gemm_bf16<<<dim3(1, 4, 1), 256, 0, stream>>>(h2c, cwob, outCls, h2c, cwob, outCls,
                                                 1024, 81, 81, 1, 0, 0, 0);

  // ---- stage 3: conv tower. Border zeros AFTER fc1 (partials aliased cbufB)
  //      and AFTER roialign (cbufA aliases featN). ----
  k_zero_border<<<dim3(480, 3), 256, 0, stream>>>(r14p, cbufA, cbufB);
  k_conv3m<1><<<dim3(2, 784), 256, 0, stream>>>(r14p, wTb + 0 * 589824, cbufA);
  k_conv3m<1><<<dim3(2, 784), 256, 0, stream>>>(cbufA, wTb + 1 * 589824, cbufB);
  k_conv3m<1><<<dim3(2, 784), 256, 0, stream>>>(cbufB, wTb + 2 * 589824, cbufA);
  k_conv3m<0><<<dim3(2, 784), 256, 0, stream>>>(cbufA, wTb + 3 * 589824, dflat);

  // ---- stage 4: deconv taps + 1x1 class proj scatter ----
  for (int r = 0; r < 2; ++r)
    for (int s = 0; s < 2; ++s) {
      int tap = r * 2 + s;
      k_gemm_bf16<<<dim3(2, 784, 1), 256, 0, stream>>>(
          dflat, wdb + tap * 65536, ddec, dflat, wdb, ddec,
          256, 256, 256, 0, 1, 0, 0);
      k_gemm_bf16<<<dim3(1, 784, 1), 256, 0, stream>>>(
          ddec, mprTb, outMask, ddec, mprTb, outMask,
          256, 81, 0, 2, 0, r, s);
    }
}

// Round 2
// 1676.708 us; speedup vs baseline: 1.0427x; 1.0064x over previous
//
#include <hip/hip_runtime.h>
#include <stdint.h>

#define BB 2
#define CC 256
#define HH 200
#define WW 336
#define NROI 512
#define NCLS 81

typedef __attribute__((ext_vector_type(8))) short bf16x8;
typedef __attribute__((ext_vector_type(4))) float f32x4;

__device__ inline unsigned short f2bf(float f) {
  unsigned int u = __builtin_bit_cast(unsigned int, f);
  u += 0x7fffu + ((u >> 16) & 1u);
  return (unsigned short)(u >> 16);
}
__device__ inline float bf2f(unsigned short h) {
  unsigned int u = ((unsigned int)h) << 16;
  return __builtin_bit_cast(float, u);
}

// async global->LDS, 16 B per lane; LDS dest = wave-uniform base + lane*16
__device__ inline void gl_lds(const void* gp, void* lp) {
  __builtin_amdgcn_global_load_lds(
      (const __attribute__((address_space(1))) unsigned int*)gp,
      (__attribute__((address_space(3))) unsigned int*)lp, 16, 0, 0);
}

// ---------------------------------------------------------------------------
// feat NCHW fp32 -> NHWC bf16, tiled transpose. grid (2100, 8, 2), block 256
// ---------------------------------------------------------------------------
__global__ void k_nchw2nhwc(const float* __restrict__ src, unsigned short* __restrict__ dst) {
  __shared__ float t[32][33];
  int b = blockIdx.z;
  int p0 = blockIdx.x * 32;
  int c0 = blockIdx.y * 32;
  int tx = threadIdx.x & 31, ty = threadIdx.x >> 5;
  const float* s = src + (size_t)b * CC * HH * WW;
  unsigned short* d = dst + (size_t)b * CC * HH * WW;
#pragma unroll
  for (int q = 0; q < 4; ++q)
    t[ty + q * 8][tx] = s[(size_t)(c0 + ty + q * 8) * (HH * WW) + p0 + tx];
  __syncthreads();
#pragma unroll
  for (int q = 0; q < 4; ++q)
    d[(size_t)(p0 + ty + q * 8) * CC + c0 + tx] = f2bf(t[tx][ty + q * 8]);
}

// ---------------------------------------------------------------------------
// Weight repacks (fp32 -> bf16, Bt layout [out][in] so GEMM reads k-contig)
// ---------------------------------------------------------------------------
// 4 conv weights OIHW [256,256,3,3] -> wTb[conv][t][o][c]; grid (2304, 4)
__global__ void k_repack_convw4(const float* __restrict__ w0, const float* __restrict__ w1,
                                const float* __restrict__ w2, const float* __restrict__ w3,
                                unsigned short* __restrict__ wT) {
  int d = blockIdx.x * 256 + threadIdx.x;  // 9*256*256
  if (d >= 589824) return;
  int which = blockIdx.y;
  const float* w = (which == 0) ? w0 : (which == 1) ? w1 : (which == 2) ? w2 : w3;
  int c = d & 255, o = (d >> 8) & 255, t = d >> 16;
  wT[(size_t)which * 589824 + d] = f2bf(w[o * 2304 + c * 9 + t]);
}

// deconv IOHW [256,256,2,2] -> wdb[tap][o][c], spatially flipped:
// out[2i+r,2j+s,o] += x[i,j,c]*mdc[c,o,1-r,1-s]
__global__ void k_repack_deconv(const float* __restrict__ mdc, unsigned short* __restrict__ wd) {
  int d = blockIdx.x * 256 + threadIdx.x;  // 4*256*256
  if (d >= 262144) return;
  int c = d & 255, o = (d >> 8) & 255, tap = d >> 16;
  int r = tap >> 1, s = tap & 1;
  wd[d] = f2bf(mdc[c * 1024 + o * 4 + (1 - r) * 2 + (1 - s)]);
}

// mpr [81,256] -> mprTb[o][c], o padded to 128 with zeros
__global__ void k_repack_mpr(const float* __restrict__ mpr, unsigned short* __restrict__ mT) {
  int d = blockIdx.x * 256 + threadIdx.x;  // 128*256
  if (d >= 32768) return;
  int c = d & 255, o = d >> 8;
  mT[d] = (o < 81) ? f2bf(mpr[o * 256 + c]) : (unsigned short)0;
}

// w1 [12544][1024] -> dst[n][k'] with k' = s*256 + c  (orig k = c*49+s)
// grid (49, 8, 32), block 256
__global__ void k_repack_w1(const float* __restrict__ src, unsigned short* __restrict__ dst) {
  __shared__ float t[32][33];
  int s = blockIdx.x;
  int c0 = blockIdx.y * 32;
  int n0 = blockIdx.z * 32;
  int tx = threadIdx.x & 31, ty = threadIdx.x >> 5;
#pragma unroll
  for (int q = 0; q < 4; ++q)
    t[ty + q * 8][tx] = src[(size_t)((c0 + ty + q * 8) * 49 + s) * 1024 + n0 + tx];
  __syncthreads();
#pragma unroll
  for (int q = 0; q < 4; ++q)
    dst[(size_t)(n0 + ty + q * 8) * 12544 + s * 256 + c0 + tx] = f2bf(t[tx][ty + q * 8]);
}

// generic: src [K][Nreal] f32 -> dst [Nphys][K] bf16 (rows >= Nreal zero)
__global__ void k_transpose_w(const float* __restrict__ src, unsigned short* __restrict__ dst,
                              int K, int Nreal, int Nphys) {
  __shared__ float t[32][33];
  int k0 = blockIdx.x * 32;
  int n0 = blockIdx.y * 32;
  int tx = threadIdx.x & 31, ty = threadIdx.x >> 5;
#pragma unroll
  for (int q = 0; q < 4; ++q) {
    int n = n0 + tx;
    t[ty + q * 8][tx] = (n < Nreal) ? src[(size_t)(k0 + ty + q * 8) * Nreal + n] : 0.f;
  }
  __syncthreads();
#pragma unroll
  for (int q = 0; q < 4; ++q) {
    int n = n0 + ty + q * 8;
    if (n < Nphys) dst[(size_t)n * K + k0 + tx] = f2bf(t[tx][ty + q * 8]);
  }
}

// ---------------------------------------------------------------------------
// zero the 60 border slots (16x16 pad minus 14x14 interior) of the 3 padded
// NHWC conv buffers. grid (480, 3), block 256; each block = 64 rows of 512 B.
// ---------------------------------------------------------------------------
__global__ void k_zero_border(unsigned short* __restrict__ r14p,
                              unsigned short* __restrict__ cbufA,
                              unsigned short* __restrict__ cbufB) {
  unsigned short* base = (blockIdx.y == 0) ? r14p : (blockIdx.y == 1) ? cbufA : cbufB;
  uint4 z = {0u, 0u, 0u, 0u};
#pragma unroll
  for (int q = 0; q < 8; ++q) {
    int lin = blockIdx.x * 2048 + q * 256 + threadIdx.x;
    int row = lin >> 5, u4 = lin & 31;
    int img = row / 60, b = row - img * 60;
    int y, x;
    if (b < 16) { y = 0; x = b; }
    else if (b < 32) { y = 15; x = b - 16; }
    else { int rem = b - 32; y = 1 + (rem >> 1); x = (rem & 1) * 15; }
    int slot = img * 256 + y * 16 + x;
    ((uint4*)base)[(size_t)slot * 32 + u4] = z;
  }
}

// ---------------------------------------------------------------------------
// RoIAlign from bf16 NHWC feat, bf16 out. Block per (n, s), 256 thr = channels.
// OS=7 : out r7b[n*12544 + s*256 + c]           (FC-head A, k' = s*256+c)
// OS=14: out r14p[(n*256 + (y+1)*16 + (x+1))*256 + c]  (padded conv input)
// ---------------------------------------------------------------------------
template <int OS>
__global__ void k_roialign(const unsigned short* __restrict__ featN, const float* __restrict__ boxes,
                           const int* __restrict__ bidx, unsigned short* __restrict__ out) {
  const int S = OS * OS;
  int blk = blockIdx.x;
  int n = blk / S;
  int s = blk - n * S;
  int oy = s / OS, ox = s - oy * OS;
  int c = threadIdx.x;
  float x1 = boxes[n * 4 + 0], y1 = boxes[n * 4 + 1];
  float x2 = boxes[n * 4 + 2], y2 = boxes[n * 4 + 3];
  const unsigned short* fb = featN + (size_t)bidx[n] * HH * WW * CC;
  const float P = (float)(OS * 2);
  float acc = 0.f;
#pragma unroll
  for (int sy = 0; sy < 2; ++sy)
#pragma unroll
    for (int sx = 0; sx < 2; ++sx) {
      float xs = x1 + ((float)(ox * 2 + sx) + 0.5f) / P * (x2 - x1);
      float ys = y1 + ((float)(oy * 2 + sy) + 0.5f) / P * (y2 - y1);
      xs = fminf(fmaxf(xs, 0.f), (float)(WW - 1));
      ys = fminf(fmaxf(ys, 0.f), (float)(HH - 1));
      int x0 = (int)floorf(xs);
      int y0 = (int)floorf(ys);
      int x1i = min(x0 + 1, WW - 1);
      int y1i = min(y0 + 1, HH - 1);
      float lx = xs - (float)x0, ly = ys - (float)y0;
      float f00 = bf2f(fb[((y0 * WW + x0) << 8) + c]);
      float f01 = bf2f(fb[((y0 * WW + x1i) << 8) + c]);
      float f10 = bf2f(fb[((y1i * WW + x0) << 8) + c]);
      float f11 = bf2f(fb[((y1i * WW + x1i) << 8) + c]);
      acc += f00 * (1.f - ly) * (1.f - lx) + f01 * (1.f - ly) * lx +
             f10 * ly * (1.f - lx) + f11 * ly * lx;
    }
  acc *= 0.25f;
  if (OS == 7) {
    out[(size_t)n * 12544 + s * 256 + c] = f2bf(acc);
  } else {
    int slot = n * 256 + (oy + 1) * 16 + (ox + 1);
    out[((size_t)slot << 8) + c] = f2bf(acc);
  }
}

// ---------------------------------------------------------------------------
// bf16 MFMA GEMM, m97 structure: 128x128 tile, BK=32, 4 waves 2x2,
// global_load_lds width 16, A [M][K] bf16, Bt [Nphys][K] bf16.
// mode 0: bf16 out [gm*ldO+gn] (opt relu)
// mode 1: fp32 out [gm*ldO+gn], guarded gn < Nreal
// mode 2: fp32 mask-scatter, guarded gn < Nreal
// ---------------------------------------------------------------------------
#define TM 128
#define TN 128
#define TK 32

__global__ __launch_bounds__(256) void k_gemm_bf16(
    const unsigned short* __restrict__ A0, const unsigned short* __restrict__ Bt0, void* __restrict__ O0p,
    const unsigned short* __restrict__ A1, const unsigned short* __restrict__ Bt1, void* __restrict__ O1p,
    int K, int Nreal, int ldO, int mode, int relu, int ki, int kj) {
  const unsigned short* A = blockIdx.z ? A1 : A0;
  const unsigned short* Bt = blockIdx.z ? Bt1 : Bt0;
  void* Op = blockIdx.z ? O1p : O0p;

  __shared__ unsigned short As[TM * TK];
  __shared__ unsigned short Bs[TN * TK];

  int tid = threadIdx.x, lane = tid & 63, w = tid >> 6;
  int m0 = blockIdx.y * TM, n0 = blockIdx.x * TN;
  int lr = lane >> 2, lc = (lane & 3) * 8;

  const unsigned short* aP[2];
  const unsigned short* bP[2];
  unsigned short* asL[2];
  unsigned short* bsL[2];
#pragma unroll
  for (int s = 0; s < 2; ++s) {
    int seg = w * 2 + s;
    aP[s] = A + (size_t)(m0 + seg * 16 + lr) * K + lc;
    bP[s] = Bt + (size_t)(n0 + seg * 16 + lr) * K + lc;
    asL[s] = As + seg * 512;
    bsL[s] = Bs + seg * 512;
  }

  f32x4 acc[4][4] = {};
  int wm = (w & 1) * 64, wn = (w >> 1) * 64;
  int qa = (lane >> 4) * 8, rl = lane & 15;

  for (int k0 = 0; k0 < K; k0 += TK) {
    gl_lds(aP[0], asL[0]);
    gl_lds(aP[1], asL[1]);
    gl_lds(bP[0], bsL[0]);
    gl_lds(bP[1], bsL[1]);
    aP[0] += TK; aP[1] += TK; bP[0] += TK; bP[1] += TK;
    __syncthreads();
    bf16x8 af[4], bfr[4];
#pragma unroll
    for (int i = 0; i < 4; ++i)
      af[i] = *(const bf16x8*)&As[(wm + i * 16 + rl) * TK + qa];
#pragma unroll
    for (int j = 0; j < 4; ++j)
      bfr[j] = *(const bf16x8*)&Bs[(wn + j * 16 + rl) * TK + qa];
#pragma unroll
    for (int i = 0; i < 4; ++i)
#pragma unroll
      for (int j = 0; j < 4; ++j)
        acc[i][j] = __builtin_amdgcn_mfma_f32_16x16x32_bf16(af[i], bfr[j], acc[i][j], 0, 0, 0);
    __syncthreads();
  }

  int col = lane & 15, rquad = (lane >> 4) * 4;
#pragma unroll
  for (int i = 0; i < 4; ++i) {
#pragma unroll
    for (int j = 0; j < 4; ++j) {
      int gn = n0 + wn + j * 16 + col;
#pragma unroll
      for (int r = 0; r < 4; ++r) {
        int gm = m0 + wm + i * 16 + rquad + r;
        float v = acc[i][j][r];
        if (relu) v = fmaxf(v, 0.f);
        if (mode == 0) {
          ((unsigned short*)Op)[(size_t)gm * ldO + gn] = f2bf(v);
        } else if (mode == 1) {
          if (gn < Nreal) ((float*)Op)[(size_t)gm * ldO + gn] = v;
        } else {
          if (gn < Nreal) {
            int nimg = gm / 196;
            int s2 = gm - nimg * 196;
            int ii = s2 / 14, jj = s2 - ii * 14;
            size_t dst = (((size_t)nimg * 81 + gn) * 28 + (2 * ii + ki)) * 28 + (2 * jj + kj);
            ((float*)Op)[dst] = v;
          }
        }
      }
    }
  }
}

// ---------------------------------------------------------------------------
// FC1 split-K: M=512, N=1024, K=12544 split into 8 slices of 1568.
// grid (8, 4, 16): z -> head = z>>3 (0:box 1:cls), slice = z&7.
// fp32 partials Opart[(head*8+slice)*524288 + m*1024 + n].
// ---------------------------------------------------------------------------
__global__ __launch_bounds__(256) void k_fc1(
    const unsigned short* __restrict__ A, const unsigned short* __restrict__ Bb,
    const unsigned short* __restrict__ Bc, float* __restrict__ Opart) {
  int head = blockIdx.z >> 3, slice = blockIdx.z & 7;
  const unsigned short* Bt = head ? Bc : Bb;

  __shared__ unsigned short As[TM * TK];
  __shared__ unsigned short Bs[TN * TK];

  int tid = threadIdx.x, lane = tid & 63, w = tid >> 6;
  int m0 = blockIdx.y * TM, n0 = blockIdx.x * TN;
  int lr = lane >> 2, lc = (lane & 3) * 8;
  int kbase = slice * 1568;

  const unsigned short* aP[2];
  const unsigned short* bP[2];
  unsigned short* asL[2];
  unsigned short* bsL[2];
#pragma unroll
  for (int s = 0; s < 2; ++s) {
    int seg = w * 2 + s;
    aP[s] = A + (size_t)(m0 + seg * 16 + lr) * 12544 + kbase + lc;
    bP[s] = Bt + (size_t)(n0 + seg * 16 + lr) * 12544 + kbase + lc;
    asL[s] = As + seg * 512;
    bsL[s] = Bs + seg * 512;
  }

  f32x4 acc[4][4] = {};
  int wm = (w & 1) * 64, wn = (w >> 1) * 64;
  int qa = (lane >> 4) * 8, rl = lane & 15;

  for (int k0 = 0; k0 < 1568; k0 += TK) {
    gl_lds(aP[0], asL[0]);
    gl_lds(aP[1], asL[1]);
    gl_lds(bP[0], bsL[0]);
    gl_lds(bP[1], bsL[1]);
    aP[0] += TK; aP[1] += TK; bP[0] += TK; bP[1] += TK;
    __syncthreads();
    bf16x8 af[4], bfr[4];
#pragma unroll
    for (int i = 0; i < 4; ++i)
      af[i] = *(const bf16x8*)&As[(wm + i * 16 + rl) * TK + qa];
#pragma unroll
    for (int j = 0; j < 4; ++j)
      bfr[j] = *(const bf16x8*)&Bs[(wn + j * 16 + rl) * TK + qa];
#pragma unroll
    for (int i = 0; i < 4; ++i)
#pragma unroll
      for (int j = 0; j < 4; ++j)
        acc[i][j] = __builtin_amdgcn_mfma_f32_16x16x32_bf16(af[i], bfr[j], acc[i][j], 0, 0, 0);
    __syncthreads();
  }

  float* O = Opart + (size_t)(head * 8 + slice) * 524288;
  int col = lane & 15, rquad = (lane >> 4) * 4;
#pragma unroll
  for (int i = 0; i < 4; ++i)
#pragma unroll
    for (int j = 0; j < 4; ++j) {
      int gn = n0 + wn + j * 16 + col;
#pragma unroll
      for (int r = 0; r < 4; ++r) {
        int gm = m0 + wm + i * 16 + rquad + r;
        O[(size_t)gm * 1024 + gn] = acc[i][j][r];
      }
    }
}

// reduce 8 split-K partials, relu, -> bf16 h1. grid (2048, 2), block 256.
__global__ void k_fc1red(const float* __restrict__ part, unsigned short* __restrict__ h1b,
                         unsigned short* __restrict__ h1c) {
  int head = blockIdx.y;
  int i = blockIdx.x * 256 + threadIdx.x;  // < 524288
  const float* p = part + (size_t)head * 8 * 524288 + i;
  float s = 0.f;
#pragma unroll
  for (int q = 0; q < 8; ++q) s += p[(size_t)q * 524288];
  unsigned short* h = head ? h1c : h1b;
  h[i] = f2bf(fmaxf(s, 0.f));
}

// ---------------------------------------------------------------------------
// conv3x3 SAME + relu, 256x256-tile deep-pipelined MFMA GEMM.
// M = 100352 (392 blocks of 256 rows), N = 256 (full width), K = 36 steps of
// BK=64 (channel-block-outer, tap-inner: s = cb*9 + t).
// 8 waves (2M x 4N), per-wave out 128x64, acc[8][4] f32x4.
// LDS: double-buffered A[256][64] + B[256][64] bf16 = 128 KiB.
// Pipeline: stage(s+1) via global_load_lds is issued BEFORE computing step s;
// the single end-of-step __syncthreads drains vmcnt after ~2400 cyc of MFMA,
// so the L2-resident loads (~200-400 cyc) are already landed -> drain is free.
// T2 swizzle: LDS rows are 128 B (16-way read conflict if linear). Staging
// writes global chunk (row, ch8^(row&7)) at LDS chunk (row, ch8) (involution,
// pre-swizzled SOURCE since gl_lds dest must be linear); reads XOR the chunk
// index -> 16-lane frag read spreads over all 8 bank-quads, 2-way = free.
// T5: setprio(1) around each 32-MFMA cluster.
// XCD swizzle: 392 = 8*49, bijective chunked.
// PADOUT=1: write padded interior; PADOUT=0: flat [100352][256].
// ---------------------------------------------------------------------------
template <int PADOUT>
__global__ __launch_bounds__(512, 2) void k_conv256(const unsigned short* __restrict__ act,
                                                    const unsigned short* __restrict__ wt,
                                                    unsigned short* __restrict__ out) {
  __shared__ unsigned short As[2][16384];  // [buf][256 rows][64 ch]
  __shared__ unsigned short Bs[2][16384];

  int tid = threadIdx.x, lane = tid & 63, wv = tid >> 6;
  int mt = (blockIdx.x & 7) * 49 + (blockIdx.x >> 3);
  int m0 = mt * 256;

  // ---- staging precompute: thread owns chunks qa = q*512+tid (16 B each) ----
  int r8 = tid >> 3;                       // row-within-64 for this thread
  int j8 = ((tid & 7) ^ (r8 & 7)) * 8;     // swizzled source chunk (elements)
  int slotA[4];
  int bElem[4];
#pragma unroll
  for (int q = 0; q < 4; ++q) {
    int row = q * 64 + r8;
    int gm = m0 + row;
    int n = gm / 196;
    int rem = gm - n * 196;
    int y = rem / 14, x = rem - y * 14;
    slotA[q] = n * 256 + (y + 1) * 16 + (x + 1);
    bElem[q] = row * 256 + j8;
  }
  int ldsU = wv * 512;  // wave-uniform element base (lane*16 B added by HW)

  // ---- read-side precompute ----
  int wr = wv >> 2, wc = wv & 3;
  int rl = lane & 15, lg = lane >> 4, e = lane & 7;
  int swz0 = ((lg) ^ e) * 8;        // ks=0: chunk lg
  int swz1 = ((4 + lg) ^ e) * 8;    // ks=1: chunk 4+lg

  f32x4 acc[8][4] = {};

#define STAGE(S, D)                                                               \
  do {                                                                            \
    int cb_ = (S) / 9;                                                            \
    int t_ = (S) - cb_ * 9;                                                       \
    int ky_ = t_ / 3, kx_ = t_ - ky_ * 3;                                         \
    int tapd_ = (ky_ - 1) * 16 + (kx_ - 1);                                       \
    int coff_ = cb_ * 64;                                                         \
    _Pragma("unroll") for (int q = 0; q < 4; ++q)                                 \
        gl_lds(act + (size_t)(slotA[q] + tapd_) * 256 + coff_ + j8,               \
               &As[D][q * 4096 + ldsU]);                                          \
    _Pragma("unroll") for (int q = 0; q < 4; ++q)                                 \
        gl_lds(wt + (size_t)t_ * 65536 + bElem[q] + coff_,                        \
               &Bs[D][q * 4096 + ldsU]);                                          \
  } while (0)

  STAGE(0, 0);
  __syncthreads();

  for (int s = 0; s < 36; ++s) {
    int cur = s & 1;
    if (s + 1 < 36) STAGE(s + 1, cur ^ 1);
    const unsigned short* Ab = As[cur];
    const unsigned short* Bb = Bs[cur];
#pragma unroll
    for (int ks = 0; ks < 2; ++ks) {
      int sw = ks ? swz1 : swz0;
      bf16x8 a[8], b[4];
#pragma unroll
      for (int fi = 0; fi < 8; ++fi)
        a[fi] = *(const bf16x8*)&Ab[(wr * 128 + fi * 16 + rl) * 64 + sw];
#pragma unroll
      for (int fj = 0; fj < 4; ++fj)
        b[fj] = *(const bf16x8*)&Bb[(wc * 64 + fj * 16 + rl) * 64 + sw];
      __builtin_amdgcn_s_setprio(1);
#pragma unroll
      for (int fi = 0; fi < 8; ++fi)
#pragma unroll
        for (int fj = 0; fj < 4; ++fj)
          acc[fi][fj] = __builtin_amdgcn_mfma_f32_16x16x32_bf16(a[fi], b[fj], acc[fi][fj], 0, 0, 0);
      __builtin_amdgcn_s_setprio(0);
    }
    __syncthreads();
  }
#undef STAGE

  // ---- epilogue ----
  int col = lane & 15, rquad = lg * 4;
#pragma unroll
  for (int fi = 0; fi < 8; ++fi) {
#pragma unroll
    for (int r = 0; r < 4; ++r) {
      int gm = m0 + wr * 128 + fi * 16 + rquad + r;
      size_t rowbase;
      if (PADOUT) {
        int n = gm / 196;
        int rem = gm - n * 196;
        int y = rem / 14, x = rem - y * 14;
        rowbase = ((size_t)(n * 256 + (y + 1) * 16 + (x + 1))) << 8;
      } else {
        rowbase = (size_t)gm << 8;
      }
#pragma unroll
      for (int fj = 0; fj < 4; ++fj) {
        int gn = wc * 64 + fj * 16 + col;
        out[rowbase + gn] = f2bf(fmaxf(acc[fi][fj][r], 0.f));
      }
    }
  }
}

// ---------------------------------------------------------------------------
// kernel_launch
// ---------------------------------------------------------------------------
extern "C" void kernel_launch(void* const* d_in, const int* in_sizes, int n_in,
                              void* d_out, int out_size, void* d_ws, size_t ws_size,
                              hipStream_t stream) {
  (void)in_sizes; (void)n_in; (void)out_size; (void)ws_size;
  const float* feat = (const float*)d_in[0];
  const float* boxes = (const float*)d_in[1];
  const float* bw1 = (const float*)d_in[2];
  const float* bw2 = (const float*)d_in[3];
  const float* bwo = (const float*)d_in[4];
  const float* cw1 = (const float*)d_in[5];
  const float* cw2 = (const float*)d_in[6];
  const float* cwo = (const float*)d_in[7];
  const float* m1 = (const float*)d_in[8];
  const float* m2 = (const float*)d_in[9];
  const float* m3 = (const float*)d_in[10];
  const float* m4 = (const float*)d_in[11];
  const float* mdc = (const float*)d_in[12];
  const float* mpr = (const float*)d_in[13];
  const int* bidx = (const int*)d_in[14];

  // ---- workspace layout (bytes; total 384,761,856 <= proven 386,465,792) ----
  char* p = (char*)d_ws;
  unsigned short* featN = (unsigned short*)p; p += 68812800;  // bf16 NHWC feat
  unsigned short* cbufA = featN;                              // alias (67,108,864 B)
  unsigned short* cbufB = (unsigned short*)p; p += 67108864;
  float* fc1part = (float*)cbufB;                             // alias (33,554,432 B)
  unsigned short* r14p = (unsigned short*)p;  p += 67108864;  // padded conv input
  unsigned short* dflat = (unsigned short*)p; p += 51380224;  // conv4 out, flat
  unsigned short* ddec = (unsigned short*)p;  p += 51380224;  // deconv tap out
  unsigned short* r7b = (unsigned short*)p;   p += 12845056;  // [512][12544]
  unsigned short* h1b = (unsigned short*)p;   p += 1048576;
  unsigned short* h1c = (unsigned short*)p;   p += 1048576;
  unsigned short* h2b = (unsigned short*)p;   p += 1048576;
  unsigned short* h2c = (unsigned short*)p;   p += 1048576;
  unsigned short* wTb = (unsigned short*)p;   p += 4718592;   // 4 convs [9][o][c]
  unsigned short* wdb = (unsigned short*)p;   p += 524288;    // [4][o][c]
  unsigned short* mprTb = (unsigned short*)p; p += 65536;     // [128][256]
  unsigned short* bw1b = (unsigned short*)p;  p += 25690112;  // [1024][12544]
  unsigned short* cw1b = (unsigned short*)p;  p += 25690112;
  unsigned short* bw2b = (unsigned short*)p;  p += 2097152;   // [1024][1024]
  unsigned short* cw2b = (unsigned short*)p;  p += 2097152;
  unsigned short* bwob = (unsigned short*)p;  p += 786432;    // [384][1024]
  unsigned short* cwob = (unsigned short*)p;  p += 262144;    // [128][1024]

  float* outBox = (float*)d_out;              // [512][324]
  float* outCls = outBox + 512 * 324;         // [512][81]
  float* outMask = outCls + 512 * 81;         // [512][81][28][28]

  // ---- stage 0: layout transforms ----
  k_nchw2nhwc<<<dim3(2100, 8, 2), 256, 0, stream>>>(feat, featN);
  k_repack_convw4<<<dim3(2304, 4), 256, 0, stream>>>(m1, m2, m3, m4, wTb);
  k_repack_deconv<<<dim3(1024), 256, 0, stream>>>(mdc, wdb);
  k_repack_mpr<<<dim3(128), 256, 0, stream>>>(mpr, mprTb);
  k_repack_w1<<<dim3(49, 8, 32), 256, 0, stream>>>(bw1, bw1b);
  k_repack_w1<<<dim3(49, 8, 32), 256, 0, stream>>>(cw1, cw1b);
  k_transpose_w<<<dim3(32, 32), 256, 0, stream>>>(bw2, bw2b, 1024, 1024, 1024);
  k_transpose_w<<<dim3(32, 32), 256, 0, stream>>>(cw2, cw2b, 1024, 1024, 1024);
  k_transpose_w<<<dim3(32, 12), 256, 0, stream>>>(bwo, bwob, 1024, 324, 384);
  k_transpose_w<<<dim3(32, 4), 256, 0, stream>>>(cwo, cwob, 1024, 81, 128);

  // ---- stage 1: RoIAlign (interiors; borders of r14p zeroed later) ----
  k_roialign<7><<<dim3(512 * 49), 256, 0, stream>>>(featN, boxes, bidx, r7b);
  k_roialign<14><<<dim3(512 * 196), 256, 0, stream>>>(featN, boxes, bidx, r14p);

  // ---- stage 2: FC heads. FC1 split-K=8 over both heads (partials alias cbufB) ----
  k_fc1<<<dim3(8, 4, 16), 256, 0, stream>>>(r7b, bw1b, cw1b, fc1part);
  k_fc1red<<<dim3(2048, 2), 256, 0, stream>>>(fc1part, h1b, h1c);
  k_gemm_bf16<<<dim3(8, 4, 2), 256, 0, stream>>>(h1b, bw2b, h2b, h1c, cw2b, h2c,
                                                 1024, 1024, 1024, 0, 1, 0, 0);
  k_gemm_bf16<<<dim3(3, 4, 1), 256, 0, stream>>>(h2b, bwob, outBox, h2b, bwob, outBox,
                                                 1024, 324, 324, 1, 0, 0, 0);
  k_gemm_bf16<<<dim3(1, 4, 1), 256, 0, stream>>>(h2c, cwob, outCls, h2c, cwob, outCls,
                                                 1024, 81, 81, 1, 0, 0, 0);

  // ---- stage 3: conv tower (deep-pipelined 256x256 tiles). Border zeros AFTER
  //      fc1 (partials aliased cbufB) and AFTER roialign (cbufA aliases featN). ----
  k_zero_border<<<dim3(480, 3), 256, 0, stream>>>(r14p, cbufA, cbufB);
  k_conv256<1><<<dim3(392), 512, 0, stream>>>(r14p, wTb + 0 * 589824, cbufA);
  k_conv256<1><<<dim3(392), 512, 0, stream>>>(cbufA, wTb + 1 * 589824, cbufB);
  k_conv256<1><<<dim3(392), 512, 0, stream>>>(cbufB, wTb + 2 * 589824, cbufA);
  k_conv256<0><<<dim3(392), 512, 0, stream>>>(cbufA, wTb + 3 * 589824, dflat);

  // ---- stage 4: deconv taps + 1x1 class proj scatter ----
  for (int r = 0; r < 2; ++r)
    for (int s = 0; s < 2; ++s) {
      int tap = r * 2 + s;
      k_gemm_bf16<<<dim3(2, 784, 1), 256, 0, stream>>>(
          dflat, wdb + tap * 65536, ddec, dflat, wdb, ddec,
          256, 256, 256, 0, 1, 0, 0);
      k_gemm_bf16<<<dim3(1, 784, 1), 256, 0, stream>>>(
          ddec, mprTb, outMask, ddec, mprTb, outMask,
          256, 81, 0, 2, 0, r, s);
    }
}

// Round 3
// 1651.194 us; speedup vs baseline: 1.0588x; 1.0155x over previous
//
#include <hip/hip_runtime.h>
#include <stdint.h>

#define BB 2
#define CC 256
#define HH 200
#define WW 336
#define NROI 512
#define NCLS 81

typedef __attribute__((ext_vector_type(8))) short bf16x8;
typedef __attribute__((ext_vector_type(4))) float f32x4;

__device__ inline unsigned short f2bf(float f) {
  unsigned int u = __builtin_bit_cast(unsigned int, f);
  u += 0x7fffu + ((u >> 16) & 1u);
  return (unsigned short)(u >> 16);
}
__device__ inline float bf2f(unsigned short h) {
  unsigned int u = ((unsigned int)h) << 16;
  return __builtin_bit_cast(float, u);
}

// async global->LDS, 16 B per lane; LDS dest = wave-uniform base + lane*16
__device__ inline void gl_lds(const void* gp, void* lp) {
  __builtin_amdgcn_global_load_lds(
      (const __attribute__((address_space(1))) unsigned int*)gp,
      (__attribute__((address_space(3))) unsigned int*)lp, 16, 0, 0);
}

// ---------------------------------------------------------------------------
// feat NCHW fp32 -> NHWC bf16, tiled transpose. grid (2100, 8, 2), block 256
// ---------------------------------------------------------------------------
__global__ void k_nchw2nhwc(const float* __restrict__ src, unsigned short* __restrict__ dst) {
  __shared__ float t[32][33];
  int b = blockIdx.z;
  int p0 = blockIdx.x * 32;
  int c0 = blockIdx.y * 32;
  int tx = threadIdx.x & 31, ty = threadIdx.x >> 5;
  const float* s = src + (size_t)b * CC * HH * WW;
  unsigned short* d = dst + (size_t)b * CC * HH * WW;
#pragma unroll
  for (int q = 0; q < 4; ++q)
    t[ty + q * 8][tx] = s[(size_t)(c0 + ty + q * 8) * (HH * WW) + p0 + tx];
  __syncthreads();
#pragma unroll
  for (int q = 0; q < 4; ++q)
    d[(size_t)(p0 + ty + q * 8) * CC + c0 + tx] = f2bf(t[tx][ty + q * 8]);
}

// ---------------------------------------------------------------------------
// Weight repacks (fp32 -> bf16, Bt layout [out][in] so GEMM reads k-contig)
// ---------------------------------------------------------------------------
// 4 conv weights OIHW [256,256,3,3] -> wTb[conv][t][o][c]; grid (2304, 4)
__global__ void k_repack_convw4(const float* __restrict__ w0, const float* __restrict__ w1,
                                const float* __restrict__ w2, const float* __restrict__ w3,
                                unsigned short* __restrict__ wT) {
  int d = blockIdx.x * 256 + threadIdx.x;  // 9*256*256
  if (d >= 589824) return;
  int which = blockIdx.y;
  const float* w = (which == 0) ? w0 : (which == 1) ? w1 : (which == 2) ? w2 : w3;
  int c = d & 255, o = (d >> 8) & 255, t = d >> 16;
  wT[(size_t)which * 589824 + d] = f2bf(w[o * 2304 + c * 9 + t]);
}

// deconv IOHW [256,256,2,2] -> wdb[tap][o][c], spatially flipped:
// out[2i+r,2j+s,o] += x[i,j,c]*mdc[c,o,1-r,1-s]
__global__ void k_repack_deconv(const float* __restrict__ mdc, unsigned short* __restrict__ wd) {
  int d = blockIdx.x * 256 + threadIdx.x;  // 4*256*256
  if (d >= 262144) return;
  int c = d & 255, o = (d >> 8) & 255, tap = d >> 16;
  int r = tap >> 1, s = tap & 1;
  wd[d] = f2bf(mdc[c * 1024 + o * 4 + (1 - r) * 2 + (1 - s)]);
}

// mpr [81,256] -> mprTb[o][c], o padded to 128 with zeros
__global__ void k_repack_mpr(const float* __restrict__ mpr, unsigned short* __restrict__ mT) {
  int d = blockIdx.x * 256 + threadIdx.x;  // 128*256
  if (d >= 32768) return;
  int c = d & 255, o = d >> 8;
  mT[d] = (o < 81) ? f2bf(mpr[o * 256 + c]) : (unsigned short)0;
}

// w1 [12544][1024] -> dst[n][k'] with k' = s*256 + c  (orig k = c*49+s)
// grid (49, 8, 32), block 256
__global__ void k_repack_w1(const float* __restrict__ src, unsigned short* __restrict__ dst) {
  __shared__ float t[32][33];
  int s = blockIdx.x;
  int c0 = blockIdx.y * 32;
  int n0 = blockIdx.z * 32;
  int tx = threadIdx.x & 31, ty = threadIdx.x >> 5;
#pragma unroll
  for (int q = 0; q < 4; ++q)
    t[ty + q * 8][tx] = src[(size_t)((c0 + ty + q * 8) * 49 + s) * 1024 + n0 + tx];
  __syncthreads();
#pragma unroll
  for (int q = 0; q < 4; ++q)
    dst[(size_t)(n0 + ty + q * 8) * 12544 + s * 256 + c0 + tx] = f2bf(t[tx][ty + q * 8]);
}

// generic: src [K][Nreal] f32 -> dst [Nphys][K] bf16 (rows >= Nreal zero)
__global__ void k_transpose_w(const float* __restrict__ src, unsigned short* __restrict__ dst,
                              int K, int Nreal, int Nphys) {
  __shared__ float t[32][33];
  int k0 = blockIdx.x * 32;
  int n0 = blockIdx.y * 32;
  int tx = threadIdx.x & 31, ty = threadIdx.x >> 5;
#pragma unroll
  for (int q = 0; q < 4; ++q) {
    int n = n0 + tx;
    t[ty + q * 8][tx] = (n < Nreal) ? src[(size_t)(k0 + ty + q * 8) * Nreal + n] : 0.f;
  }
  __syncthreads();
#pragma unroll
  for (int q = 0; q < 4; ++q) {
    int n = n0 + ty + q * 8;
    if (n < Nphys) dst[(size_t)n * K + k0 + tx] = f2bf(t[tx][ty + q * 8]);
  }
}

// ---------------------------------------------------------------------------
// zero the 60 border slots (16x16 pad minus 14x14 interior) of the 3 padded
// NHWC conv buffers. grid (480, 3), block 256; each block = 64 rows of 512 B.
// ---------------------------------------------------------------------------
__global__ void k_zero_border(unsigned short* __restrict__ r14p,
                              unsigned short* __restrict__ cbufA,
                              unsigned short* __restrict__ cbufB) {
  unsigned short* base = (blockIdx.y == 0) ? r14p : (blockIdx.y == 1) ? cbufA : cbufB;
  uint4 z = {0u, 0u, 0u, 0u};
#pragma unroll
  for (int q = 0; q < 8; ++q) {
    int lin = blockIdx.x * 2048 + q * 256 + threadIdx.x;
    int row = lin >> 5, u4 = lin & 31;
    int img = row / 60, b = row - img * 60;
    int y, x;
    if (b < 16) { y = 0; x = b; }
    else if (b < 32) { y = 15; x = b - 16; }
    else { int rem = b - 32; y = 1 + (rem >> 1); x = (rem & 1) * 15; }
    int slot = img * 256 + y * 16 + x;
    ((uint4*)base)[(size_t)slot * 32 + u4] = z;
  }
}

// ---------------------------------------------------------------------------
// RoIAlign from bf16 NHWC feat, bf16 out. Block per (n, s), 256 thr = channels.
// OS=7 : out r7b[n*12544 + s*256 + c]           (FC-head A, k' = s*256+c)
// OS=14: out r14p[(n*256 + (y+1)*16 + (x+1))*256 + c]  (padded conv input)
// ---------------------------------------------------------------------------
template <int OS>
__global__ void k_roialign(const unsigned short* __restrict__ featN, const float* __restrict__ boxes,
                           const int* __restrict__ bidx, unsigned short* __restrict__ out) {
  const int S = OS * OS;
  int blk = blockIdx.x;
  int n = blk / S;
  int s = blk - n * S;
  int oy = s / OS, ox = s - oy * OS;
  int c = threadIdx.x;
  float x1 = boxes[n * 4 + 0], y1 = boxes[n * 4 + 1];
  float x2 = boxes[n * 4 + 2], y2 = boxes[n * 4 + 3];
  const unsigned short* fb = featN + (size_t)bidx[n] * HH * WW * CC;
  const float P = (float)(OS * 2);
  float acc = 0.f;
#pragma unroll
  for (int sy = 0; sy < 2; ++sy)
#pragma unroll
    for (int sx = 0; sx < 2; ++sx) {
      float xs = x1 + ((float)(ox * 2 + sx) + 0.5f) / P * (x2 - x1);
      float ys = y1 + ((float)(oy * 2 + sy) + 0.5f) / P * (y2 - y1);
      xs = fminf(fmaxf(xs, 0.f), (float)(WW - 1));
      ys = fminf(fmaxf(ys, 0.f), (float)(HH - 1));
      int x0 = (int)floorf(xs);
      int y0 = (int)floorf(ys);
      int x1i = min(x0 + 1, WW - 1);
      int y1i = min(y0 + 1, HH - 1);
      float lx = xs - (float)x0, ly = ys - (float)y0;
      float f00 = bf2f(fb[((y0 * WW + x0) << 8) + c]);
      float f01 = bf2f(fb[((y0 * WW + x1i) << 8) + c]);
      float f10 = bf2f(fb[((y1i * WW + x0) << 8) + c]);
      float f11 = bf2f(fb[((y1i * WW + x1i) << 8) + c]);
      acc += f00 * (1.f - ly) * (1.f - lx) + f01 * (1.f - ly) * lx +
             f10 * ly * (1.f - lx) + f11 * ly * lx;
    }
  acc *= 0.25f;
  if (OS == 7) {
    out[(size_t)n * 12544 + s * 256 + c] = f2bf(acc);
  } else {
    int slot = n * 256 + (oy + 1) * 16 + (ox + 1);
    out[((size_t)slot << 8) + c] = f2bf(acc);
  }
}

// ---------------------------------------------------------------------------
// bf16 MFMA GEMM, m97 structure: 128x128 tile, BK=32, 4 waves 2x2,
// global_load_lds width 16, A [M][K] bf16, Bt [Nphys][K] bf16.
// mode 0: bf16 out [gm*ldO+gn] (opt relu)
// mode 1: fp32 out [gm*ldO+gn], guarded gn < Nreal
// mode 2: fp32 mask-scatter, guarded gn < Nreal
// ---------------------------------------------------------------------------
#define TM 128
#define TN 128
#define TK 32

__global__ __launch_bounds__(256) void k_gemm_bf16(
    const unsigned short* __restrict__ A0, const unsigned short* __restrict__ Bt0, void* __restrict__ O0p,
    const unsigned short* __restrict__ A1, const unsigned short* __restrict__ Bt1, void* __restrict__ O1p,
    int K, int Nreal, int ldO, int mode, int relu, int ki, int kj) {
  const unsigned short* A = blockIdx.z ? A1 : A0;
  const unsigned short* Bt = blockIdx.z ? Bt1 : Bt0;
  void* Op = blockIdx.z ? O1p : O0p;

  __shared__ unsigned short As[TM * TK];
  __shared__ unsigned short Bs[TN * TK];

  int tid = threadIdx.x, lane = tid & 63, w = tid >> 6;
  int m0 = blockIdx.y * TM, n0 = blockIdx.x * TN;
  int lr = lane >> 2, lc = (lane & 3) * 8;

  const unsigned short* aP[2];
  const unsigned short* bP[2];
  unsigned short* asL[2];
  unsigned short* bsL[2];
#pragma unroll
  for (int s = 0; s < 2; ++s) {
    int seg = w * 2 + s;
    aP[s] = A + (size_t)(m0 + seg * 16 + lr) * K + lc;
    bP[s] = Bt + (size_t)(n0 + seg * 16 + lr) * K + lc;
    asL[s] = As + seg * 512;
    bsL[s] = Bs + seg * 512;
  }

  f32x4 acc[4][4] = {};
  int wm = (w & 1) * 64, wn = (w >> 1) * 64;
  int qa = (lane >> 4) * 8, rl = lane & 15;

  for (int k0 = 0; k0 < K; k0 += TK) {
    gl_lds(aP[0], asL[0]);
    gl_lds(aP[1], asL[1]);
    gl_lds(bP[0], bsL[0]);
    gl_lds(bP[1], bsL[1]);
    aP[0] += TK; aP[1] += TK; bP[0] += TK; bP[1] += TK;
    __syncthreads();
    bf16x8 af[4], bfr[4];
#pragma unroll
    for (int i = 0; i < 4; ++i)
      af[i] = *(const bf16x8*)&As[(wm + i * 16 + rl) * TK + qa];
#pragma unroll
    for (int j = 0; j < 4; ++j)
      bfr[j] = *(const bf16x8*)&Bs[(wn + j * 16 + rl) * TK + qa];
#pragma unroll
    for (int i = 0; i < 4; ++i)
#pragma unroll
      for (int j = 0; j < 4; ++j)
        acc[i][j] = __builtin_amdgcn_mfma_f32_16x16x32_bf16(af[i], bfr[j], acc[i][j], 0, 0, 0);
    __syncthreads();
  }

  int col = lane & 15, rquad = (lane >> 4) * 4;
#pragma unroll
  for (int i = 0; i < 4; ++i) {
#pragma unroll
    for (int j = 0; j < 4; ++j) {
      int gn = n0 + wn + j * 16 + col;
#pragma unroll
      for (int r = 0; r < 4; ++r) {
        int gm = m0 + wm + i * 16 + rquad + r;
        float v = acc[i][j][r];
        if (relu) v = fmaxf(v, 0.f);
        if (mode == 0) {
          ((unsigned short*)Op)[(size_t)gm * ldO + gn] = f2bf(v);
        } else if (mode == 1) {
          if (gn < Nreal) ((float*)Op)[(size_t)gm * ldO + gn] = v;
        } else {
          if (gn < Nreal) {
            int nimg = gm / 196;
            int s2 = gm - nimg * 196;
            int ii = s2 / 14, jj = s2 - ii * 14;
            size_t dst = (((size_t)nimg * 81 + gn) * 28 + (2 * ii + ki)) * 28 + (2 * jj + kj);
            ((float*)Op)[dst] = v;
          }
        }
      }
    }
  }
}

// ---------------------------------------------------------------------------
// FC1 split-K: M=512, N=1024, K=12544 split into 8 slices of 1568.
// grid (8, 4, 16): z -> head = z>>3 (0:box 1:cls), slice = z&7.
// fp32 partials Opart[(head*8+slice)*524288 + m*1024 + n].
// ---------------------------------------------------------------------------
__global__ __launch_bounds__(256) void k_fc1(
    const unsigned short* __restrict__ A, const unsigned short* __restrict__ Bb,
    const unsigned short* __restrict__ Bc, float* __restrict__ Opart) {
  int head = blockIdx.z >> 3, slice = blockIdx.z & 7;
  const unsigned short* Bt = head ? Bc : Bb;

  __shared__ unsigned short As[TM * TK];
  __shared__ unsigned short Bs[TN * TK];

  int tid = threadIdx.x, lane = tid & 63, w = tid >> 6;
  int m0 = blockIdx.y * TM, n0 = blockIdx.x * TN;
  int lr = lane >> 2, lc = (lane & 3) * 8;
  int kbase = slice * 1568;

  const unsigned short* aP[2];
  const unsigned short* bP[2];
  unsigned short* asL[2];
  unsigned short* bsL[2];
#pragma unroll
  for (int s = 0; s < 2; ++s) {
    int seg = w * 2 + s;
    aP[s] = A + (size_t)(m0 + seg * 16 + lr) * 12544 + kbase + lc;
    bP[s] = Bt + (size_t)(n0 + seg * 16 + lr) * 12544 + kbase + lc;
    asL[s] = As + seg * 512;
    bsL[s] = Bs + seg * 512;
  }

  f32x4 acc[4][4] = {};
  int wm = (w & 1) * 64, wn = (w >> 1) * 64;
  int qa = (lane >> 4) * 8, rl = lane & 15;

  for (int k0 = 0; k0 < 1568; k0 += TK) {
    gl_lds(aP[0], asL[0]);
    gl_lds(aP[1], asL[1]);
    gl_lds(bP[0], bsL[0]);
    gl_lds(bP[1], bsL[1]);
    aP[0] += TK; aP[1] += TK; bP[0] += TK; bP[1] += TK;
    __syncthreads();
    bf16x8 af[4], bfr[4];
#pragma unroll
    for (int i = 0; i < 4; ++i)
      af[i] = *(const bf16x8*)&As[(wm + i * 16 + rl) * TK + qa];
#pragma unroll
    for (int j = 0; j < 4; ++j)
      bfr[j] = *(const bf16x8*)&Bs[(wn + j * 16 + rl) * TK + qa];
#pragma unroll
    for (int i = 0; i < 4; ++i)
#pragma unroll
      for (int j = 0; j < 4; ++j)
        acc[i][j] = __builtin_amdgcn_mfma_f32_16x16x32_bf16(af[i], bfr[j], acc[i][j], 0, 0, 0);
    __syncthreads();
  }

  float* O = Opart + (size_t)(head * 8 + slice) * 524288;
  int col = lane & 15, rquad = (lane >> 4) * 4;
#pragma unroll
  for (int i = 0; i < 4; ++i)
#pragma unroll
    for (int j = 0; j < 4; ++j) {
      int gn = n0 + wn + j * 16 + col;
#pragma unroll
      for (int r = 0; r < 4; ++r) {
        int gm = m0 + wm + i * 16 + rquad + r;
        O[(size_t)gm * 1024 + gn] = acc[i][j][r];
      }
    }
}

// reduce 8 split-K partials, relu, -> bf16 h1. grid (2048, 2), block 256.
__global__ void k_fc1red(const float* __restrict__ part, unsigned short* __restrict__ h1b,
                         unsigned short* __restrict__ h1c) {
  int head = blockIdx.y;
  int i = blockIdx.x * 256 + threadIdx.x;  // < 524288
  const float* p = part + (size_t)head * 8 * 524288 + i;
  float s = 0.f;
#pragma unroll
  for (int q = 0; q < 8; ++q) s += p[(size_t)q * 524288];
  unsigned short* h = head ? h1c : h1b;
  h[i] = f2bf(fmaxf(s, 0.f));
}

// ---------------------------------------------------------------------------
// conv3x3 SAME + relu, 256x256-tile MFMA GEMM with the m201 4-phase/K-tile
// counted-vmcnt schedule (T3+T4), T2 swizzle, T5 setprio.
// M = 100352 (392 blocks of 256 rows), N = 256, K = 36 tiles of BK=64
// (channel-block-outer, tap-inner: s = cb*9 + t).
// 8 waves (2M x 4N), per-wave out 128x64, acc[8][4] f32x4.
// LDS: double-buffered A[256][64] + B[256][64] bf16 = 128 KiB, 1 block/CU.
//
// Schedule per K-tile s (buffers cur=s&1, nxt=cur^1):
//   issue A-halves of tile s+1 (4 gl_lds)
//   s_waitcnt vmcnt(4)   <- waits only B(s) (issued 3 phases ago); NEVER 0
//   barrier               (tile gate: all threads' tile-s stages landed)
//   q0: ds a[qi0](8)+b0(4); BAR; prio1; 16 MFMA; prio0; BAR
//   q1: ds b1(4); issue B-halves of tile s+1 (4 gl_lds); BAR; 16 MFMA; BAR
//   q2: ds a[qi1](8); BAR; 16 MFMA; BAR
//   q3: 16 MFMA; BAR  (tile end: fences stage(s+2) writes vs buf reads)
// Per-thread VMEM FIFO = [A(s+1) x4 ... B(s+1) x4], so vmcnt(4) at tile top
// == "all of tile s landed" exactly (FIFO retire order, m135).
//
// T2 swizzle: LDS rows are 128 B (16-way conflict if linear). Staging writes
// global chunk (row, ch8^(row&7)) at LDS chunk (row, ch8) (pre-swizzled
// SOURCE, since gl_lds dest must be linear); reads XOR the chunk index.
// Verified conflict-free (R1: SQ_LDS_BANK_CONFLICT = 0).
// XCD swizzle: 392 = 8*49, bijective chunked.
// PADOUT=1: write padded interior; PADOUT=0: flat [100352][256].
// ---------------------------------------------------------------------------
template <int PADOUT>
__global__ __launch_bounds__(512, 2) void k_conv256(const unsigned short* __restrict__ act,
                                                    const unsigned short* __restrict__ wt,
                                                    unsigned short* __restrict__ out) {
  __shared__ unsigned short As[2][16384];  // [buf][256 rows][64 ch]
  __shared__ unsigned short Bs[2][16384];

  int tid = threadIdx.x, lane = tid & 63, wv = tid >> 6;
  int mt = (blockIdx.x & 7) * 49 + (blockIdx.x >> 3);
  int m0 = mt * 256;

  // ---- staging precompute: thread owns chunks q*512+tid (16 B each) ----
  int r8 = tid >> 3;                       // row-within-64 for this thread
  int j8 = ((tid & 7) ^ (r8 & 7)) * 8;     // swizzled source chunk (elements)
  int slotA[4];
  int bElem[4];
#pragma unroll
  for (int q = 0; q < 4; ++q) {
    int row = q * 64 + r8;
    int gm = m0 + row;
    int n = gm / 196;
    int rem = gm - n * 196;
    int y = rem / 14, x = rem - y * 14;
    slotA[q] = n * 256 + (y + 1) * 16 + (x + 1);
    bElem[q] = row * 256 + j8;
  }
  int ldsU = wv * 512;  // wave-uniform element base (lane*16 B added by HW)

  // ---- read-side precompute ----
  int wr = wv >> 2, wc = wv & 3;
  int rl = lane & 15, lg = lane >> 4, e = lane & 7;
  int s0 = (lg ^ e) * 8;          // ks=0: chunk lg
  int s1 = ((4 + lg) ^ e) * 8;    // ks=1: chunk 4+lg
  int rowA = (wr * 128 + rl) * 64;
  int rowB = (wc * 64 + rl) * 64;

  f32x4 acc[8][4] = {};

#define STAGE_A(S, D)                                                             \
  do {                                                                            \
    int cb_ = (S) / 9;                                                            \
    int t_ = (S) - cb_ * 9;                                                       \
    int ky_ = t_ / 3, kx_ = t_ - ky_ * 3;                                         \
    int tapd_ = (ky_ - 1) * 16 + (kx_ - 1);                                       \
    int coff_ = cb_ * 64;                                                         \
    _Pragma("unroll") for (int q = 0; q < 4; ++q)                                 \
        gl_lds(act + (size_t)(slotA[q] + tapd_) * 256 + coff_ + j8,               \
               &As[D][q * 4096 + ldsU]);                                          \
  } while (0)

#define STAGE_B(S, D)                                                             \
  do {                                                                            \
    int cb_ = (S) / 9;                                                            \
    int t_ = (S) - cb_ * 9;                                                       \
    int coff_ = cb_ * 64;                                                         \
    _Pragma("unroll") for (int q = 0; q < 4; ++q)                                 \
        gl_lds(wt + (size_t)t_ * 65536 + bElem[q] + coff_,                        \
               &Bs[D][q * 4096 + ldsU]);                                          \
  } while (0)

#define LOAD_A(QI)                                                                \
  _Pragma("unroll") for (int fi = 0; fi < 4; ++fi) {                              \
    a[fi][0] = *(const bf16x8*)&Ab[rowA + (QI)*4096 + fi * 1024 + s0];            \
    a[fi][1] = *(const bf16x8*)&Ab[rowA + (QI)*4096 + fi * 1024 + s1];            \
  }

#define LOAD_B(QJ, BREG)                                                          \
  _Pragma("unroll") for (int fj = 0; fj < 2; ++fj) {                              \
    BREG[fj][0] = *(const bf16x8*)&Bb[rowB + (QJ)*2048 + fj * 1024 + s0];         \
    BREG[fj][1] = *(const bf16x8*)&Bb[rowB + (QJ)*2048 + fj * 1024 + s1];         \
  }

#define QUAD(QI, QJ, BREG)                                                        \
  __builtin_amdgcn_s_setprio(1);                                                  \
  _Pragma("unroll") for (int fi = 0; fi < 4; ++fi)                                \
  _Pragma("unroll") for (int fj = 0; fj < 2; ++fj) {                              \
    acc[(QI)*4 + fi][(QJ)*2 + fj] = __builtin_amdgcn_mfma_f32_16x16x32_bf16(      \
        a[fi][0], BREG[fj][0], acc[(QI)*4 + fi][(QJ)*2 + fj], 0, 0, 0);           \
    acc[(QI)*4 + fi][(QJ)*2 + fj] = __builtin_amdgcn_mfma_f32_16x16x32_bf16(      \
        a[fi][1], BREG[fj][1], acc[(QI)*4 + fi][(QJ)*2 + fj], 0, 0, 0);           \
  }                                                                               \
  __builtin_amdgcn_s_setprio(0);

  // prologue: stage tile 0 (A then B; 8 loads in flight)
  STAGE_A(0, 0);
  STAGE_B(0, 0);

  for (int s = 0; s < 36; ++s) {
    int cur = s & 1, nxt = cur ^ 1;
    const unsigned short* Ab = As[cur];
    const unsigned short* Bb = Bs[cur];
    if (s < 35) {
      STAGE_A(s + 1, nxt);
      asm volatile("s_waitcnt vmcnt(4)" ::: "memory");
    } else {
      asm volatile("s_waitcnt vmcnt(0)" ::: "memory");
    }
    __builtin_amdgcn_s_barrier();
    __builtin_amdgcn_sched_barrier(0);

    bf16x8 a[4][2], b0[2][2], b1[2][2];
    // ---- q0: quadrant (qi=0, qj=0) ----
    LOAD_A(0);
    LOAD_B(0, b0);
    __builtin_amdgcn_s_barrier();
    QUAD(0, 0, b0);
    __builtin_amdgcn_s_barrier();
    // ---- q1: quadrant (qi=0, qj=1); stage B-halves of tile s+1 ----
    LOAD_B(1, b1);
    if (s < 35) STAGE_B(s + 1, nxt);
    __builtin_amdgcn_s_barrier();
    QUAD(0, 1, b1);
    __builtin_amdgcn_s_barrier();
    // ---- q2: quadrant (qi=1, qj=0) ----
    LOAD_A(1);
    __builtin_amdgcn_s_barrier();
    QUAD(1, 0, b0);
    __builtin_amdgcn_s_barrier();
    // ---- q3: quadrant (qi=1, qj=1) ----
    QUAD(1, 1, b1);
    __builtin_amdgcn_s_barrier();
    __builtin_amdgcn_sched_barrier(0);
  }
#undef STAGE_A
#undef STAGE_B
#undef LOAD_A
#undef LOAD_B
#undef QUAD

  // ---- epilogue ----
  int col = lane & 15, rquad = lg * 4;
#pragma unroll
  for (int fi = 0; fi < 8; ++fi) {
#pragma unroll
    for (int r = 0; r < 4; ++r) {
      int gm = m0 + wr * 128 + fi * 16 + rquad + r;
      size_t rowbase;
      if (PADOUT) {
        int n = gm / 196;
        int rem = gm - n * 196;
        int y = rem / 14, x = rem - y * 14;
        rowbase = ((size_t)(n * 256 + (y + 1) * 16 + (x + 1))) << 8;
      } else {
        rowbase = (size_t)gm << 8;
      }
#pragma unroll
      for (int fj = 0; fj < 4; ++fj) {
        int gn = wc * 64 + fj * 16 + col;
        out[rowbase + gn] = f2bf(fmaxf(acc[fi][fj][r], 0.f));
      }
    }
  }
}

// ---------------------------------------------------------------------------
// kernel_launch
// ---------------------------------------------------------------------------
extern "C" void kernel_launch(void* const* d_in, const int* in_sizes, int n_in,
                              void* d_out, int out_size, void* d_ws, size_t ws_size,
                              hipStream_t stream) {
  (void)in_sizes; (void)n_in; (void)out_size; (void)ws_size;
  const float* feat = (const float*)d_in[0];
  const float* boxes = (const float*)d_in[1];
  const float* bw1 = (const float*)d_in[2];
  const float* bw2 = (const float*)d_in[3];
  const float* bwo = (const float*)d_in[4];
  const float* cw1 = (const float*)d_in[5];
  const float* cw2 = (const float*)d_in[6];
  const float* cwo = (const float*)d_in[7];
  const float* m1 = (const float*)d_in[8];
  const float* m2 = (const float*)d_in[9];
  const float* m3 = (const float*)d_in[10];
  const float* m4 = (const float*)d_in[11];
  const float* mdc = (const float*)d_in[12];
  const float* mpr = (const float*)d_in[13];
  const int* bidx = (const int*)d_in[14];

  // ---- workspace layout (bytes; total 384,761,856 <= proven 386,465,792) ----
  char* p = (char*)d_ws;
  unsigned short* featN = (unsigned short*)p; p += 68812800;  // bf16 NHWC feat
  unsigned short* cbufA = featN;                              // alias (67,108,864 B)
  unsigned short* cbufB = (unsigned short*)p; p += 67108864;
  float* fc1part = (float*)cbufB;                             // alias (33,554,432 B)
  unsigned short* r14p = (unsigned short*)p;  p += 67108864;  // padded conv input
  unsigned short* dflat = (unsigned short*)p; p += 51380224;  // conv4 out, flat
  unsigned short* ddec = (unsigned short*)p;  p += 51380224;  // deconv tap out
  unsigned short* r7b = (unsigned short*)p;   p += 12845056;  // [512][12544]
  unsigned short* h1b = (unsigned short*)p;   p += 1048576;
  unsigned short* h1c = (unsigned short*)p;   p += 1048576;
  unsigned short* h2b = (unsigned short*)p;   p += 1048576;
  unsigned short* h2c = (unsigned short*)p;   p += 1048576;
  unsigned short* wTb = (unsigned short*)p;   p += 4718592;   // 4 convs [9][o][c]
  unsigned short* wdb = (unsigned short*)p;   p += 524288;    // [4][o][c]
  unsigned short* mprTb = (unsigned short*)p; p += 65536;     // [128][256]
  unsigned short* bw1b = (unsigned short*)p;  p += 25690112;  // [1024][12544]
  unsigned short* cw1b = (unsigned short*)p;  p += 25690112;
  unsigned short* bw2b = (unsigned short*)p;  p += 2097152;   // [1024][1024]
  unsigned short* cw2b = (unsigned short*)p;  p += 2097152;
  unsigned short* bwob = (unsigned short*)p;  p += 786432;    // [384][1024]
  unsigned short* cwob = (unsigned short*)p;  p += 262144;    // [128][1024]

  float* outBox = (float*)d_out;              // [512][324]
  float* outCls = outBox + 512 * 324;         // [512][81]
  float* outMask = outCls + 512 * 81;         // [512][81][28][28]

  // ---- stage 0: layout transforms ----
  k_nchw2nhwc<<<dim3(2100, 8, 2), 256, 0, stream>>>(feat, featN);
  k_repack_convw4<<<dim3(2304, 4), 256, 0, stream>>>(m1, m2, m3, m4, wTb);
  k_repack_deconv<<<dim3(1024), 256, 0, stream>>>(mdc, wdb);
  k_repack_mpr<<<dim3(128), 256, 0, stream>>>(mpr, mprTb);
  k_repack_w1<<<dim3(49, 8, 32), 256, 0, stream>>>(bw1, bw1b);
  k_repack_w1<<<dim3(49, 8, 32), 256, 0, stream>>>(cw1, cw1b);
  k_transpose_w<<<dim3(32, 32), 256, 0, stream>>>(bw2, bw2b, 1024, 1024, 1024);
  k_transpose_w<<<dim3(32, 32), 256, 0, stream>>>(cw2, cw2b, 1024, 1024, 1024);
  k_transpose_w<<<dim3(32, 12), 256, 0, stream>>>(bwo, bwob, 1024, 324, 384);
  k_transpose_w<<<dim3(32, 4), 256, 0, stream>>>(cwo, cwob, 1024, 81, 128);

  // ---- stage 1: RoIAlign (interiors; borders of r14p zeroed later) ----
  k_roialign<7><<<dim3(512 * 49), 256, 0, stream>>>(featN, boxes, bidx, r7b);
  k_roialign<14><<<dim3(512 * 196), 256, 0, stream>>>(featN, boxes, bidx, r14p);

  // ---- stage 2: FC heads. FC1 split-K=8 over both heads (partials alias cbufB) ----
  k_fc1<<<dim3(8, 4, 16), 256, 0, stream>>>(r7b, bw1b, cw1b, fc1part);
  k_fc1red<<<dim3(2048, 2), 256, 0, stream>>>(fc1part, h1b, h1c);
  k_gemm_bf16<<<dim3(8, 4, 2), 256, 0, stream>>>(h1b, bw2b, h2b, h1c, cw2b, h2c,
                                                 1024, 1024, 1024, 0, 1, 0, 0);
  k_gemm_bf16<<<dim3(3, 4, 1), 256, 0, stream>>>(h2b, bwob, outBox, h2b, bwob, outBox,
                                                 1024, 324, 324, 1, 0, 0, 0);
  k_gemm_bf16<<<dim3(1, 4, 1), 256, 0, stream>>>(h2c, cwob, outCls, h2c, cwob, outCls,
                                                 1024, 81, 81, 1, 0, 0, 0);

  // ---- stage 3: conv tower (4-phase counted-vmcnt 256x256 tiles). Border zeros
  //      AFTER fc1 (partials aliased cbufB) and AFTER roialign (cbufA aliases featN). ----
  k_zero_border<<<dim3(480, 3), 256, 0, stream>>>(r14p, cbufA, cbufB);
  k_conv256<1><<<dim3(392), 512, 0, stream>>>(r14p, wTb + 0 * 589824, cbufA);
  k_conv256<1><<<dim3(392), 512, 0, stream>>>(cbufA, wTb + 1 * 589824, cbufB);
  k_conv256<1><<<dim3(392), 512, 0, stream>>>(cbufB, wTb + 2 * 589824, cbufA);
  k_conv256<0><<<dim3(392), 512, 0, stream>>>(cbufA, wTb + 3 * 589824, dflat);

  // ---- stage 4: deconv taps + 1x1 class proj scatter ----
  for (int r = 0; r < 2; ++r)
    for (int s = 0; s < 2; ++s) {
      int tap = r * 2 + s;
      k_gemm_bf16<<<dim3(2, 784, 1), 256, 0, stream>>>(
          dflat, wdb + tap * 65536, ddec, dflat, wdb, ddec,
          256, 256, 256, 0, 1, 0, 0);
      k_gemm_bf16<<<dim3(1, 784, 1), 256, 0, stream>>>(
          ddec, mprTb, outMask, ddec, mprTb, outMask,
          256, 81, 0, 2, 0, r, s);
    }
}